// Round 1
// baseline (457.505 us; speedup 1.0000x reference)
//
#include <hip/hip_runtime.h>
#include <hip/hip_bf16.h>
#include <stdint.h>

// Problem constants: B=32, T=256, M=2048, C=F=256, K=3 (pad 1), NB=256
#define DUR_OFF 16777216
#define PIT_OFF 16785408
#define ENE_OFF 16850944
#define MEL_OFF 16916480

typedef __attribute__((ext_vector_type(8))) short short8;
typedef __attribute__((ext_vector_type(4))) float f32x4;

__device__ __forceinline__ void async16(const void* g, void* l) {
  __builtin_amdgcn_global_load_lds((__attribute__((address_space(1))) void*)g,
                                   (__attribute__((address_space(3))) void*)l, 16, 0, 0);
}

__device__ __forceinline__ unsigned short bfu(float f) {
  __hip_bfloat16 h = __float2bfloat16(f);
  return __builtin_bit_cast(unsigned short, h);
}

// Zero the two pad rows (t=-1 and t=L) of a padded [B][L+2][256] bf16 buffer.
__global__ void zero_pads_kernel(__hip_bfloat16* __restrict__ buf, int L) {
  int b = blockIdx.x >> 1;
  size_t row = (size_t)b * (L + 2) + ((blockIdx.x & 1) ? (L + 1) : 0);
  buf[row * 256 + threadIdx.x] = __float2bfloat16(0.0f);
}

// w [F=256][C=256][3] fp32 (torch OIH) -> wp [f][k*256+c] bf16 ([256][768])
__global__ void pack_w_kernel(const float* __restrict__ w, __hip_bfloat16* __restrict__ wp) {
  int f = blockIdx.x, c = threadIdx.x;
  const float* src = w + ((size_t)f * 256 + c) * 3;
#pragma unroll
  for (int k = 0; k < 3; ++k)
    wp[(size_t)f * 768 + k * 256 + c] = __float2bfloat16(src[k]);
}

// x [32][256][256] f32 -> xb [32][258][256] bf16 (row t -> padded row t+1)
__global__ void cvt_pad_kernel(const float* __restrict__ x, __hip_bfloat16* __restrict__ xb) {
  int idx = blockIdx.x * 256 + threadIdx.x;  // one float4 each; grid covers exactly
  float4 v = ((const float4*)x)[idx];
  int c4 = idx & 63;
  int rowi = idx >> 6;
  int b = rowi >> 8, t = rowi & 255;
  ushort4 o;
  o.x = bfu(v.x); o.y = bfu(v.y); o.z = bfu(v.z); o.w = bfu(v.w);
  ((ushort4*)(xb + ((size_t)b * 258 + t + 1) * 256))[c4] = o;
}

// Per-batch inclusive cumsum of true_duration; also mel_len = min(total, 2048) as float.
__global__ void cumsum_kernel(const int* __restrict__ dur, int* __restrict__ cs,
                              float* __restrict__ mel) {
  __shared__ int s[256];
  int b = blockIdx.x, t = threadIdx.x;
  s[t] = dur[b * 256 + t];
  __syncthreads();
  for (int off = 1; off < 256; off <<= 1) {
    int add = (t >= off) ? s[t - off] : 0;
    __syncthreads();
    s[t] += add;
    __syncthreads();
  }
  cs[b * 256 + t] = s[t];
  if (t == 255) {
    int tot = s[255];
    mel[b] = (float)(tot < 2048 ? tot : 2048);
  }
}

// Length regulate: frame m <- token idx = searchsorted(cs, m, 'right'), zero if invalid.
// Writes f32 rows to d_out (final outputs base) and bf16 rows to padded M1 buffer.
__global__ void gather_kernel(const float* __restrict__ x, const int* __restrict__ cs,
                              float* __restrict__ outF, __hip_bfloat16* __restrict__ outB) {
  __shared__ int scs[256];
  __shared__ int sidx[64];
  __shared__ int sval[64];
  int bch = blockIdx.x >> 5;        // 32 chunks of 64 frames per batch
  int m0 = (blockIdx.x & 31) << 6;
  int tid = threadIdx.x;
  scs[tid] = cs[bch * 256 + tid];
  __syncthreads();
  int total = scs[255];
  if (tid < 64) {
    int m = m0 + tid;
    int lo = 0, hi = 256;
    while (lo < hi) { int mid = (lo + hi) >> 1; if (scs[mid] <= m) lo = mid + 1; else hi = mid; }
    sidx[tid] = lo < 255 ? lo : 255;
    sval[tid] = (m < total);
  }
  __syncthreads();
  int lane = tid & 63, rs = tid >> 6;
  for (int r = rs; r < 64; r += 4) {
    float4 v = make_float4(0.f, 0.f, 0.f, 0.f);
    if (sval[r]) v = ((const float4*)(x + ((size_t)bch * 256 + sidx[r]) * 256))[lane];
    ((float4*)(outF + ((size_t)bch * 2048 + m0 + r) * 256))[lane] = v;
    ushort4 o;
    o.x = bfu(v.x); o.y = bfu(v.y); o.z = bfu(v.z); o.w = bfu(v.w);
    ((ushort4*)(outB + ((size_t)bch * 2050 + m0 + r + 1) * 256))[lane] = o;
  }
}

// outF[b,m,:] += emb[searchsorted(q, val[b,m], 'right')]; optional bf16 copy to padded buf.
__global__ void addemb_kernel(const float* __restrict__ val, const float* __restrict__ q,
                              const float* __restrict__ emb, float* __restrict__ outF,
                              __hip_bfloat16* __restrict__ outB) {
  __shared__ float sq[255];
  __shared__ int sidx[64];
  int bch = blockIdx.x >> 5;
  int m0 = (blockIdx.x & 31) << 6;
  int tid = threadIdx.x;
  if (tid < 255) sq[tid] = q[tid];
  __syncthreads();
  if (tid < 64) {
    float xv = val[bch * 2048 + m0 + tid];
    int lo = 0, hi = 255;
    while (lo < hi) { int mid = (lo + hi) >> 1; if (sq[mid] <= xv) lo = mid + 1; else hi = mid; }
    sidx[tid] = lo;
  }
  __syncthreads();
  int lane = tid & 63, rs = tid >> 6;
  for (int r = rs; r < 64; r += 4) {
    size_t o = ((size_t)bch * 2048 + m0 + r) * 256;
    float4 v = ((const float4*)(outF + o))[lane];
    float4 e = ((const float4*)(emb + (size_t)sidx[r] * 256))[lane];
    v.x += e.x; v.y += e.y; v.z += e.z; v.w += e.w;
    ((float4*)(outF + o))[lane] = v;
    if (outB) {
      ushort4 ob;
      ob.x = bfu(v.x); ob.y = bfu(v.y); ob.z = bfu(v.z); ob.w = bfu(v.w);
      ((ushort4*)(outB + ((size_t)bch * 2050 + m0 + r + 1) * 256))[lane] = ob;
    }
  }
}

// Fused conv1d(K=3,'same') + bias + ReLU + LayerNorm GEMM.
//   A (padded bf16 [B][L+2][256]) x Wp ([256 f][768 kk]) -> 64x256 tile per block.
// EPI==0: store LN result as bf16 into padded Hout [B][L+2][256].
// EPI==1: additionally fold Linear(F->1)+ReLU; store scalar per row to Sout [B][L].
// LDS XOR swizzle: linear global_load_lds dest, inverse-swizzled global source,
// swizzled ds_read_b128 (byte ^= (row&7)<<4 within a 128B row).
template <int EPI>
__global__ __launch_bounds__(256, 3)
void pred_gemm(const __hip_bfloat16* __restrict__ Ap, const __hip_bfloat16* __restrict__ Wp,
               const float* __restrict__ bias, const float* __restrict__ gamma,
               const float* __restrict__ beta, const float* __restrict__ wl,
               const float* __restrict__ blp, __hip_bfloat16* __restrict__ Hout,
               float* __restrict__ Sout, int L) {
  __shared__ short lA[64 * 64];    // 8 KB  [row][64] (swizzled)
  __shared__ short lB[256 * 64];   // 32 KB [f][64]   (swizzled, W^T per chunk)
  __shared__ float lred[64 * 8];
  __shared__ float lstat[64 * 2];

  const int tid = threadIdx.x;
  const int wid = tid >> 6;        // wave 0..3 = output column block
  const int lane = tid & 63;
  const int wn = wid;
  const int tiles = L >> 6;
  const int b = blockIdx.x / tiles;
  const int t0 = (blockIdx.x % tiles) << 6;

  f32x4 acc[4][4];
  const f32x4 zero4 = {0.f, 0.f, 0.f, 0.f};
#pragma unroll
  for (int i = 0; i < 4; ++i)
#pragma unroll
    for (int j = 0; j < 4; ++j) acc[i][j] = zero4;

  const char* Abase = (const char*)(Ap + ((size_t)b * (L + 2) + t0) * 256);
  const char* Bbase = (const char*)Wp;

#pragma unroll 1
  for (int kc = 0; kc < 12; ++kc) {
    const int tap = kc >> 2;              // conv tap 0..2
    const int c0b = (kc & 3) << 7;        // channel-chunk byte offset (64 bf16)
    const char* Ag = Abase + tap * 512 + c0b;
#pragma unroll
    for (int i = 0; i < 2; ++i) {
      int lofs = i * 4096 + wid * 1024 + lane * 16;
      int row = lofs >> 7, cb = lofs & 127;
      async16(Ag + (size_t)row * 512 + (cb ^ ((row & 7) << 4)), (char*)lA + lofs);
    }
    const char* Bg = Bbase + tap * 512 + c0b;
#pragma unroll
    for (int i = 0; i < 8; ++i) {
      int lofs = i * 4096 + wid * 1024 + lane * 16;
      int f = lofs >> 7, cb = lofs & 127;
      async16(Bg + (size_t)f * 1536 + (cb ^ ((f & 7) << 4)), (char*)lB + lofs);
    }
    __syncthreads();
#pragma unroll
    for (int ks = 0; ks < 2; ++ks) {
      short8 av[4], bv[4];
      const int kb = ks * 64 + ((lane >> 4) << 4);  // byte offset of this lane's 8 bf16
#pragma unroll
      for (int mi = 0; mi < 4; ++mi) {
        int row = (mi << 4) + (lane & 15);
        av[mi] = *(const short8*)((const char*)lA + row * 128 + (kb ^ ((row & 7) << 4)));
      }
#pragma unroll
      for (int ni = 0; ni < 4; ++ni) {
        int f = (wn << 6) + (ni << 4) + (lane & 15);
        bv[ni] = *(const short8*)((const char*)lB + f * 128 + (kb ^ ((f & 7) << 4)));
      }
#pragma unroll
      for (int mi = 0; mi < 4; ++mi)
#pragma unroll
        for (int ni = 0; ni < 4; ++ni)
          acc[mi][ni] =
              __builtin_amdgcn_mfma_f32_16x16x32_bf16(av[mi], bv[ni], acc[mi][ni], 0, 0, 0);
    }
    __syncthreads();
  }

  // ---- epilogue: bias + ReLU + LN stats (per-row over 256 cols) ----
  const int cb0 = (wn << 6) + (lane & 15);
  float bi[4], gg[4], bb[4];
#pragma unroll
  for (int ni = 0; ni < 4; ++ni) {
    int col = cb0 + (ni << 4);
    bi[ni] = bias[col]; gg[ni] = gamma[col]; bb[ni] = beta[col];
  }
  const int rbase = (lane >> 4) << 2;  // D row sub-offset
#pragma unroll
  for (int mi = 0; mi < 4; ++mi) {
#pragma unroll
    for (int j = 0; j < 4; ++j) {
      float s = 0.f, s2 = 0.f;
#pragma unroll
      for (int ni = 0; ni < 4; ++ni) {
        float r = fmaxf(acc[mi][ni][j] + bi[ni], 0.f);
        s += r; s2 += r * r;
      }
#pragma unroll
      for (int d = 1; d < 16; d <<= 1) { s += __shfl_xor(s, d); s2 += __shfl_xor(s2, d); }
      if ((lane & 15) == 0) {
        int row = (mi << 4) + rbase + j;
        lred[row * 8 + wn] = s;
        lred[row * 8 + 4 + wn] = s2;
      }
    }
  }
  __syncthreads();
  if (tid < 64) {
    float s = lred[tid * 8] + lred[tid * 8 + 1] + lred[tid * 8 + 2] + lred[tid * 8 + 3];
    float s2 = lred[tid * 8 + 4] + lred[tid * 8 + 5] + lred[tid * 8 + 6] + lred[tid * 8 + 7];
    float mean = s * (1.f / 256.f);
    float var = fmaxf(s2 * (1.f / 256.f) - mean * mean, 0.f);
    lstat[tid * 2] = mean;
    lstat[tid * 2 + 1] = rsqrtf(var + 1e-5f);
  }
  __syncthreads();

  if constexpr (EPI == 0) {
#pragma unroll
    for (int mi = 0; mi < 4; ++mi) {
#pragma unroll
      for (int j = 0; j < 4; ++j) {
        int row = (mi << 4) + rbase + j;
        float mean = lstat[row * 2], rstd = lstat[row * 2 + 1];
        __hip_bfloat16* hp = Hout + ((size_t)b * (L + 2) + t0 + row + 1) * 256 + cb0;
#pragma unroll
        for (int ni = 0; ni < 4; ++ni) {
          float r = fmaxf(acc[mi][ni][j] + bi[ni], 0.f);
          hp[ni << 4] = __float2bfloat16((r - mean) * rstd * gg[ni] + bb[ni]);
        }
      }
    }
  } else {
    float wlv[4];
#pragma unroll
    for (int ni = 0; ni < 4; ++ni) wlv[ni] = wl[cb0 + (ni << 4)];
#pragma unroll
    for (int mi = 0; mi < 4; ++mi) {
#pragma unroll
      for (int j = 0; j < 4; ++j) {
        int row = (mi << 4) + rbase + j;
        float mean = lstat[row * 2], rstd = lstat[row * 2 + 1];
        float ds = 0.f;
#pragma unroll
        for (int ni = 0; ni < 4; ++ni) {
          float r = fmaxf(acc[mi][ni][j] + bi[ni], 0.f);
          ds += ((r - mean) * rstd * gg[ni] + bb[ni]) * wlv[ni];
        }
#pragma unroll
        for (int d = 1; d < 16; d <<= 1) ds += __shfl_xor(ds, d);
        if ((lane & 15) == 0) lred[row * 8 + wn] = ds;
      }
    }
    __syncthreads();
    if (tid < 64) {
      float z = lred[tid * 8] + lred[tid * 8 + 1] + lred[tid * 8 + 2] + lred[tid * 8 + 3] + blp[0];
      Sout[(size_t)b * L + t0 + tid] = fmaxf(z, 0.f);
    }
  }
}

extern "C" void kernel_launch(void* const* d_in, const int* in_sizes, int n_in,
                              void* d_out, int out_size, void* d_ws, size_t ws_size,
                              hipStream_t stream) {
  const float* x = (const float*)d_in[0];
  const int* dur = (const int*)d_in[1];
  const float* tp = (const float*)d_in[2];
  const float* te = (const float*)d_in[3];
  const float* pq = (const float*)d_in[5];
  const float* eq = (const float*)d_in[6];
  const float* pemb = (const float*)d_in[37];
  const float* eemb = (const float*)d_in[38];

  char* ws = (char*)d_ws;
  __hip_bfloat16* wp[6];
  for (int i = 0; i < 6; ++i) wp[i] = (__hip_bfloat16*)(ws + (size_t)i * 393216);
  int* cs = (int*)(ws + 2359296);
  __hip_bfloat16* xb = (__hip_bfloat16*)(ws + 2392064);     // [32][258][256]
  __hip_bfloat16* h1dp = (__hip_bfloat16*)(ws + 6619136);   // [32][258][256]
  __hip_bfloat16* M1 = (__hip_bfloat16*)(ws + 10846208);    // [32][2050][256] out0 / h1_ep
  __hip_bfloat16* M2 = (__hip_bfloat16*)(ws + 44433408);    // [32][2050][256] h1_pp / out1

  float* out = (float*)d_out;

  // zero pad rows of all padded buffers (ws is re-poisoned before each call)
  zero_pads_kernel<<<64, 256, 0, stream>>>(xb, 256);
  zero_pads_kernel<<<64, 256, 0, stream>>>(h1dp, 256);
  zero_pads_kernel<<<64, 256, 0, stream>>>(M1, 2048);
  zero_pads_kernel<<<64, 256, 0, stream>>>(M2, 2048);
  // pack conv weights to bf16 [f][k*256+c]
  pack_w_kernel<<<256, 256, 0, stream>>>((const float*)d_in[7], wp[0]);
  pack_w_kernel<<<256, 256, 0, stream>>>((const float*)d_in[11], wp[1]);
  pack_w_kernel<<<256, 256, 0, stream>>>((const float*)d_in[17], wp[2]);
  pack_w_kernel<<<256, 256, 0, stream>>>((const float*)d_in[21], wp[3]);
  pack_w_kernel<<<256, 256, 0, stream>>>((const float*)d_in[27], wp[4]);
  pack_w_kernel<<<256, 256, 0, stream>>>((const float*)d_in[31], wp[5]);
  // inputs -> bf16 padded
  cvt_pad_kernel<<<2048, 256, 0, stream>>>(x, xb);

  // duration predictor (L=256)
  pred_gemm<0><<<128, 256, 0, stream>>>(xb, wp[0], (const float*)d_in[8], (const float*)d_in[9],
                                        (const float*)d_in[10], nullptr, nullptr, h1dp, nullptr,
                                        256);
  pred_gemm<1><<<128, 256, 0, stream>>>(h1dp, wp[1], (const float*)d_in[12],
                                        (const float*)d_in[13], (const float*)d_in[14],
                                        (const float*)d_in[15], (const float*)d_in[16], nullptr,
                                        out + DUR_OFF, 256);

  // length regulate (uses TRUE durations) + mel_len
  cumsum_kernel<<<32, 256, 0, stream>>>(dur, cs, out + MEL_OFF);
  gather_kernel<<<1024, 256, 0, stream>>>(x, cs, out, M1);

  // pitch predictor (L=2048)
  pred_gemm<0><<<1024, 256, 0, stream>>>(M1, wp[2], (const float*)d_in[18], (const float*)d_in[19],
                                         (const float*)d_in[20], nullptr, nullptr, M2, nullptr,
                                         2048);
  pred_gemm<1><<<1024, 256, 0, stream>>>(M2, wp[3], (const float*)d_in[22], (const float*)d_in[23],
                                         (const float*)d_in[24], (const float*)d_in[25],
                                         (const float*)d_in[26], nullptr, out + PIT_OFF, 2048);
  // + pitch embedding (also produce bf16 out1 into M2 for energy predictor)
  addemb_kernel<<<1024, 256, 0, stream>>>(tp, pq, pemb, out, M2);

  // energy predictor (L=2048)
  pred_gemm<0><<<1024, 256, 0, stream>>>(M2, wp[4], (const float*)d_in[28], (const float*)d_in[29],
                                         (const float*)d_in[30], nullptr, nullptr, M1, nullptr,
                                         2048);
  pred_gemm<1><<<1024, 256, 0, stream>>>(M1, wp[5], (const float*)d_in[32], (const float*)d_in[33],
                                         (const float*)d_in[34], (const float*)d_in[35],
                                         (const float*)d_in[36], nullptr, out + ENE_OFF, 2048);
  // + energy embedding (final outputs, f32 only)
  addemb_kernel<<<1024, 256, 0, stream>>>(te, eq, eemb, out, nullptr);
}